// Round 9
// baseline (299.517 us; speedup 1.0000x reference)
//
#include <hip/hip_runtime.h>
#include <hip/hip_bf16.h>

// (B,C,H,W)=(8,256,128,128), M=64, K=5, S=2, nH=nW=64
#define Bq 8
#define Cq 256
#define Hq 128
#define Wq 128
#define Mq 64
#define KK 25
#define NH 64
#define NW 64
#define HWq (Hq*Wq)      // 16384
#define NHW (NH*NW)      // 4096

typedef __attribute__((ext_vector_type(8))) short short8;
typedef __attribute__((ext_vector_type(4))) float f32x4;

__device__ __forceinline__ unsigned short f2b(float f) {
  __hip_bfloat16 h = __float2bfloat16(f);      // RNE
  return __builtin_bit_cast(unsigned short, h);
}
__device__ __forceinline__ unsigned int pk2(float a, float b) {
  return (unsigned int)f2b(a) | ((unsigned int)f2b(b) << 16);
}
__device__ __forceinline__ float b2f(unsigned short u) {
  __hip_bfloat16 h = __builtin_bit_cast(__hip_bfloat16, u);
  return __bfloat162float(h);
}

// ---------------- Kernel A: 1x1 conv as bf16 MFMA GEMM, barrier-free K-loop --
// (R8 structure; epilogue now stores t1 as bf16 -> half the write traffic)
#define WS_STR 280
#define XS_STR 80
__global__ __launch_bounds__(256) void conv1x1_mfma(
    const float* __restrict__ x, const float* __restrict__ w1,
    const float* __restrict__ b1, unsigned short* __restrict__ t1) {
  __shared__ unsigned short wsl[64 * WS_STR];        // 35.8 KB  [m][c]
  __shared__ unsigned short xsl[2][4][32 * XS_STR];  // 41.0 KB  [buf][wave][px][c]
  const int tid  = threadIdx.x;
  const int lane = tid & 63;
  const int wv   = tid >> 6;          // wave 0..3 -> px base wv*32
  const int P0   = blockIdx.x << 7;   // 128 px per block
  const int b    = P0 >> 14;
  const int hw0  = P0 & (HWq - 1);

  const int quad = lane >> 4;
  const int l15  = lane & 15;

  // ---- stage ALL weights once: w1[m][c] fp32 -> wsl[m][c] bf16 (packed) ----
  {
    const int m  = tid >> 2;
    const int cb = (tid & 3) * 64;
    const float* wg = w1 + m * Cq + cb;
    unsigned int* wu = (unsigned int*)&wsl[m * WS_STR + cb];
#pragma unroll
    for (int u = 0; u < 16; ++u) {
      float4 v = *(const float4*)(wg + 4 * u);
      wu[2 * u]     = pk2(v.x, v.y);
      wu[2 * u + 1] = pk2(v.z, v.w);
    }
  }
  __syncthreads();   // the only block barrier before epilogue

  // ---- per-wave x staging maps: lane = (cp 0..31, pg 0..1) ----
  const int cp = lane >> 1;           // channel pair -> c = 2*cp, 2*cp+1
  const int pg = lane & 1;            // px half: 16 px
  const float* xb = x + (size_t)b * Cq * HWq + hw0 + wv * 32 + pg * 16;
  unsigned int* xu = (unsigned int*)&xsl[0][0][0];   // buf*4*1280 + wv*1280 + px*40 + cp

  f32x4 acc[4][2];
#pragma unroll
  for (int mt = 0; mt < 4; ++mt)
#pragma unroll
    for (int nt = 0; nt < 2; ++nt) acc[mt][nt] = (f32x4)0.f;

  float4 cur[8];
  {
    const float* g = xb + (size_t)(2 * cp) * HWq;
#pragma unroll
    for (int u = 0; u < 4; ++u) cur[u]     = *(const float4*)(g + 4 * u);
#pragma unroll
    for (int u = 0; u < 4; ++u) cur[4 + u] = *(const float4*)(g + HWq + 4 * u);
  }

  for (int cc = 0; cc < 4; ++cc) {
    {
      unsigned int* d = xu + ((cc & 1) * 4 + wv) * 1280 + cp;
#pragma unroll
      for (int u = 0; u < 4; ++u) {
        int px0 = pg * 16 + 4 * u;
        d[(px0 + 0) * 40] = pk2(cur[u].x, cur[4 + u].x);
        d[(px0 + 1) * 40] = pk2(cur[u].y, cur[4 + u].y);
        d[(px0 + 2) * 40] = pk2(cur[u].z, cur[4 + u].z);
        d[(px0 + 3) * 40] = pk2(cur[u].w, cur[4 + u].w);
      }
    }
    if (cc < 3) {
      const float* g = xb + (size_t)((cc + 1) * 64 + 2 * cp) * HWq;
#pragma unroll
      for (int u = 0; u < 4; ++u) cur[u]     = *(const float4*)(g + 4 * u);
#pragma unroll
      for (int u = 0; u < 4; ++u) cur[4 + u] = *(const float4*)(g + HWq + 4 * u);
    }
    const unsigned short* xw = &xsl[cc & 1][wv][0];
#pragma unroll
    for (int ks = 0; ks < 2; ++ks) {
      const int c0 = ks * 32 + quad * 8;
      short8 af[4], bfr[2];
#pragma unroll
      for (int mt = 0; mt < 4; ++mt)
        af[mt] = *(const short8*)&wsl[(mt * 16 + l15) * WS_STR + cc * 64 + c0];
#pragma unroll
      for (int nt = 0; nt < 2; ++nt)
        bfr[nt] = *(const short8*)&xw[(nt * 16 + l15) * XS_STR + c0];
#pragma unroll
      for (int mt = 0; mt < 4; ++mt)
#pragma unroll
        for (int nt = 0; nt < 2; ++nt)
          acc[mt][nt] = __builtin_amdgcn_mfma_f32_16x16x32_bf16(
              af[mt], bfr[nt], acc[mt][nt], 0, 0, 0);
    }
  }

  // epilogue: D row m = quad*4 + r, col px = l15 ; store bf16
#pragma unroll
  for (int mt = 0; mt < 4; ++mt) {
#pragma unroll
    for (int r = 0; r < 4; ++r) {
      int m = mt * 16 + quad * 4 + r;
      float bv = b1[m];
#pragma unroll
      for (int nt = 0; nt < 2; ++nt) {
        int px = wv * 32 + nt * 16 + l15;
        t1[((size_t)b * Mq + m) * HWq + hw0 + px] = f2b(acc[mt][nt][r] + bv);
      }
    }
  }
}

// ------- Kernel B: 3x3 s2 conv (M=64 -> 25) + bias + softmax(25) -------
// (R7 structure; t1 now bf16 -> half the read traffic)
__global__ __launch_bounds__(512) void encoder_kernel(
    const unsigned short* __restrict__ t1, const float* __restrict__ w2,
    const float* __restrict__ b2, float* __restrict__ ker) {
  __shared__ float red[8][KK][64];   // 51.2 KB, reduction only
  const int tid = threadIdx.x;
  const int ow  = tid & 63;
  const int mg  = tid >> 6;          // wave index 0..7 -> 8 m per wave
  const int b   = blockIdx.x >> 6;
  const int oh  = blockIdx.x & 63;

  float acc[KK];
#pragma unroll
  for (int k = 0; k < KK; ++k) acc[k] = 0.f;

  const unsigned short* tb = t1 + (size_t)b * Mq * HWq;
  const int iwb = 2 * ow - 1;

  for (int mi = 0; mi < 8; ++mi) {
    const int m = __builtin_amdgcn_readfirstlane(mg * 8 + mi);
    const unsigned short* tm = tb + (size_t)m * HWq;
    const float* wm = w2 + m * 9;    // w2[k*576 + m*9 + dh*3 + dw]
#pragma unroll
    for (int dh = 0; dh < 3; ++dh) {
      int ih = 2 * oh + dh - 1;
      if ((unsigned)ih < (unsigned)Hq) {
        const unsigned short* tr = tm + ih * Wq;
        float v0 = (ow > 0) ? b2f(tr[iwb]) : 0.f;
        float v1 = b2f(tr[iwb + 1]);
        float v2 = b2f(tr[iwb + 2]);
        const float* wr = wm + dh * 3;   // uniform base
#pragma unroll
        for (int k = 0; k < KK; ++k) {
          acc[k] += v0 * wr[k * 576 + 0];
          acc[k] += v1 * wr[k * 576 + 1];
          acc[k] += v2 * wr[k * 576 + 2];
        }
      }
    }
  }
#pragma unroll
  for (int k = 0; k < KK; ++k) red[mg][k][ow] = acc[k];
  __syncthreads();
  if (tid < 64) {
    float lg[KK];
#pragma unroll
    for (int k = 0; k < KK; ++k) {
      float s = b2[k];
#pragma unroll
      for (int g = 0; g < 8; ++g) s += red[g][k][tid];
      lg[k] = s;
    }
    float mx = lg[0];
#pragma unroll
    for (int k = 1; k < KK; ++k) mx = fmaxf(mx, lg[k]);
    float s = 0.f;
#pragma unroll
    for (int k = 0; k < KK; ++k) { lg[k] = __expf(lg[k] - mx); s += lg[k]; }
    float inv = 1.f / s;
    float* kb = ker + (size_t)b * KK * NHW + oh * NW + tid;
#pragma unroll
    for (int k = 0; k < KK; ++k) kb[k * NHW] = lg[k] * inv;
  }
}

// --------- Kernel C: CARAFE reassembly, LDS x-slab (unchanged from R7) ------
#define RSL_ROWS 19
#define RSL_CSZ  (RSL_ROWS * Wq)      // 2432 floats per channel slab
__global__ __launch_bounds__(256) void reassemble_kernel(
    const float* __restrict__ x, const float* __restrict__ ker,
    float* __restrict__ out) {
  __shared__ float xsl[8 * RSL_CSZ + 8];   // 76 KB + pad
  const int tid = threadIdx.x;
  const int bid = blockIdx.x;
  const int cg  = bid & 31;
  const int ohg = (bid >> 5) & 7;
  const int b   = bid >> 8;
  const int r0  = 16 * ohg - 2;            // first slab row = x row r0

  const int zlo = (r0 < 0) ? -r0 : 0;
  const int zhi = (r0 + RSL_ROWS > Hq) ? (r0 + RSL_ROWS - Hq) : 0;
  if (zlo > 0) {
    for (int c = 0; c < 8; ++c)
      for (int i = tid; i < zlo * Wq; i += 256) xsl[c * RSL_CSZ + i] = 0.f;
  }
  if (zhi > 0) {
    for (int c = 0; c < 8; ++c)
      for (int i = tid; i < zhi * Wq; i += 256)
        xsl[c * RSL_CSZ + (RSL_ROWS - zhi) * Wq + i] = 0.f;
  }
  const int vs = (r0 > 0) ? r0 : 0;
  const int ve = (r0 + RSL_ROWS < Hq) ? (r0 + RSL_ROWS) : Hq;
  const int nvec = ((ve - vs) * Wq) >> 2;          // float4 count
  const int loff = (vs - r0) * Wq;
  for (int c = 0; c < 8; ++c) {
    const float* g = x + ((size_t)(b * Cq + cg * 8 + c)) * HWq + vs * Wq;
    float* d = xsl + c * RSL_CSZ + loff;
    for (int i = tid; i < nvec; i += 256) {
      float4 v = *(const float4*)(g + 4 * i);
      *(float4*)(d + 4 * i) = v;
    }
  }

  const int ow = tid & 63;
  const int rq = tid >> 6;                 // 0..3 -> out rows oh, oh+1
  const int oh = 8 * ohg + 2 * rq;
  float kr0[KK], kr1[KK];
  const float* kb = ker + (size_t)b * KK * NHW + oh * NW + ow;
#pragma unroll
  for (int k = 0; k < KK; ++k) { kr0[k] = kb[k * NHW]; kr1[k] = kb[k * NHW + NW]; }

  __syncthreads();

  const int jb = 4 * rq;
  const bool e0 = (ow > 0);
  const bool e4 = (ow < 63);
  const float2 z2 = make_float2(0.f, 0.f);

  for (int c = 0; c < 8; ++c) {
    const float* sl = xsl + c * RSL_CSZ;
    float a0 = 0.f, a1 = 0.f;
#pragma unroll
    for (int j = 0; j < 7; ++j) {
      const float* xr = sl + (jb + j) * Wq + 2 * ow - 2;
      float2 v01 = e0 ? *(const float2*)xr : z2;        // taps -2,-1
      float2 v23 = *(const float2*)(xr + 2);            // taps  0,+1
      float  v4  = e4 ? xr[4] : 0.f;                    // tap  +2
      if (j < 5) {
        a0 += v01.x * kr0[j*5+0]; a0 += v01.y * kr0[j*5+1];
        a0 += v23.x * kr0[j*5+2]; a0 += v23.y * kr0[j*5+3];
        a0 += v4    * kr0[j*5+4];
      }
      if (j >= 2) {
        int dy = j - 2;
        a1 += v01.x * kr1[dy*5+0]; a1 += v01.y * kr1[dy*5+1];
        a1 += v23.x * kr1[dy*5+2]; a1 += v23.y * kr1[dy*5+3];
        a1 += v4    * kr1[dy*5+4];
      }
    }
    float* op = out + ((size_t)(b * Cq + cg * 8 + c)) * NHW + oh * NW + ow;
    op[0]  = a0;
    op[NW] = a1;
  }
}

extern "C" void kernel_launch(void* const* d_in, const int* in_sizes, int n_in,
                              void* d_out, int out_size, void* d_ws, size_t ws_size,
                              hipStream_t stream) {
  const float* x  = (const float*)d_in[0];
  const float* w1 = (const float*)d_in[1];
  const float* b1 = (const float*)d_in[2];
  const float* w2 = (const float*)d_in[3];
  const float* b2 = (const float*)d_in[4];
  float* out = (float*)d_out;

  unsigned short* t1 = (unsigned short*)d_ws;          // bf16, 8,388,608 elems (16.8 MB)
  float* ker = (float*)((char*)d_ws + (size_t)Bq * Mq * HWq * sizeof(unsigned short) + 256);
  // +256 pad keeps ker 16B-aligned and clear of t1

  conv1x1_mfma<<<1024, 256, 0, stream>>>(x, w1, b1, t1);
  encoder_kernel<<<Bq * NH, 512, 0, stream>>>(t1, w2, b2, ker);
  reassemble_kernel<<<2048, 256, 0, stream>>>(x, ker, out);
}